// Round 1
// baseline (141.209 us; speedup 1.0000x reference)
//
#include <hip/hip_runtime.h>
#include <hip/hip_bf16.h>

// GAT layer, MI355X. B=32, N=512, Fin=256, F=64, H=8. fp32 in / fp32 out.
// R8 = R7 (proven: 140.9us harness) + ONE change: occupancy 2->4 waves/SIMD.
//   Theory: rooflines are ~13us (HBM), ~7us (P-gen VALU), ~2us (MFMA);
//   140.9us is ~10x over all three => latency-bound at 2 waves/SIMD
//   (105KB LDS -> 1 block/CU; 512 threads = 8 waves/CU).
//   Fix: 1024-thread blocks, each wave owns 32 rows (it:4->2). Same grid,
//   same LDS, same total work; per-thread regs halve (acc 64->32 VGPRs)
//   so the 128-VGPR/thread cap of a 1024-thread block fits without spill.
// Kept from R4-R7: fused single kernel, b-major grid (XCD = b%8 so all 8
//   h-blocks of a batch share one XCD's L2 for adj/x), software-pipelined
//   adj prefetch, row sums via P@ones MFMA, exp2 with log2e folded into a,
//   mask by multiply (adj in {0,1}).

#define ALPHA  0.2f
#define ESCALE 1.4426950408889634f   // log2(e), folded into a at stage 0

typedef __bf16 bf16x8 __attribute__((ext_vector_type(8)));
typedef __bf16 bf16x4 __attribute__((ext_vector_type(4)));
typedef float  f32x4  __attribute__((ext_vector_type(4)));

#if __has_builtin(__builtin_amdgcn_exp2f)
#define EXP2(x) __builtin_amdgcn_exp2f(x)
#else
#define EXP2(x) exp2f(x)
#endif

#define HT_STRIDE 520   // 512+8: +4-bank shift per f-row
#define WT_STRIDE 264   // 256+8

struct Smem {
    __bf16 hT[64][HT_STRIDE];       // h^T tile [f][j]   66,560 B
    __bf16 WT[64][WT_STRIDE];       // W cols [n][k]     33,792 B
    float  ssrc[512], sdst[512];    //                    4,096 B
    float  asrc[64], adst[64];      //                      512 B
};                                  // 104,960 B -> 1 block/CU (16 waves)

__device__ inline bf16x8 ld8(const float* p) {
    float4 a0 = *(const float4*)p;
    float4 a1 = *(const float4*)(p + 4);
    bf16x8 r;
    r[0]=(__bf16)a0.x; r[1]=(__bf16)a0.y; r[2]=(__bf16)a0.z; r[3]=(__bf16)a0.w;
    r[4]=(__bf16)a1.x; r[5]=(__bf16)a1.y; r[6]=(__bf16)a1.z; r[7]=(__bf16)a1.w;
    return r;
}

__global__ __launch_bounds__(1024, 4) void k_gat(const float* __restrict__ x,
                                                 const float* __restrict__ adj,
                                                 const float* __restrict__ W,
                                                 const float* __restrict__ a,
                                                 float* __restrict__ out) {
    __shared__ Smem sm;
    const int b = blockIdx.x, h = blockIdx.y;    // b-major: h-blocks share XCD
    const int tid  = threadIdx.x;
    const int wave = tid >> 6, lane = tid & 63;  // wave in [0,16)
    const int quad = lane >> 4, col = lane & 15;

    // stage 0: a * log2e -> LDS; W head-slice fp32->bf16 -> LDS
    if (tid < 128) {
        float v = a[h * 128 + tid] * ESCALE;
        if (tid < 64) sm.asrc[tid] = v; else sm.adst[tid - 64] = v;
    }
    {
        int c = tid & 63, k0 = tid >> 6;             // k0 in [0,16), coalesced in c
        #pragma unroll 4
        for (int t = 0; t < 16; ++t)
            sm.WT[c][k0 + t * 16] = (__bf16)W[(long)(k0 + t * 16) * 512 + h * 64 + c];
    }
    __syncthreads();

    // stage 1: h = x[b] @ W[:,h-block] -> hT[f][j]  (MFMA 16x16x32)
    // each of 16 waves owns 32 output rows
    {
        const float* xb = x + (long)b * 512 * 256;
        f32x4 acc[2][4] = {};
        for (int ks = 0; ks < 8; ++ks) {             // K = 256
            int k0 = ks * 32 + quad * 8;
            bf16x8 av[2], bv[4];
            #pragma unroll
            for (int it = 0; it < 2; ++it)           // A[m=col][k=quad*8+u]
                av[it] = ld8(xb + (long)(wave * 32 + it * 16 + col) * 256 + k0);
            #pragma unroll
            for (int nt = 0; nt < 4; ++nt)           // B[k][n=col]
                bv[nt] = *(const bf16x8*)(&sm.WT[nt * 16 + col][k0]);
            #pragma unroll
            for (int it = 0; it < 2; ++it)
                #pragma unroll
                for (int nt = 0; nt < 4; ++nt)
                    acc[it][nt] = __builtin_amdgcn_mfma_f32_16x16x32_bf16(av[it], bv[nt], acc[it][nt], 0, 0, 0);
        }
        #pragma unroll
        for (int it = 0; it < 2; ++it)
            #pragma unroll
            for (int nt = 0; nt < 4; ++nt) {
                int f = nt * 16 + col;               // C/D: col=f, row=node
                int j = wave * 32 + it * 16 + quad * 4;
                bf16x4 pk = { (__bf16)acc[it][nt][0], (__bf16)acc[it][nt][1],
                              (__bf16)acc[it][nt][2], (__bf16)acc[it][nt][3] };
                *(bf16x4*)(&sm.hT[f][j]) = pk;
            }
    }
    __syncthreads();

    // stage 2: s_src[j], s_dst[j] = h_j . (a*log2e)
    // split across thread halves (wave-uniform branch)
    {
        int j = tid & 511;
        float s = 0.f;
        if (tid < 512) {
            #pragma unroll 8
            for (int f = 0; f < 64; ++f)
                s += (float)sm.hT[f][j] * sm.asrc[f];
            sm.ssrc[j] = s;
        } else {
            #pragma unroll 8
            for (int f = 0; f < 64; ++f)
                s += (float)sm.hT[f][j] * sm.adst[f];
            sm.sdst[j] = s;
        }
    }
    __syncthreads();

    // stage 3: P-gen + P@h MFMA, software-pipelined adj loads, no barriers
    {
        float si[2];
        const float* arow[2];
        #pragma unroll
        for (int it = 0; it < 2; ++it) {
            int i = wave * 32 + it * 16 + col;       // A-row m = lane&15
            si[it]   = sm.ssrc[i];
            arow[it] = adj + ((long)b * 512 + i) * 512;
        }
        bf16x8 ones;
        #pragma unroll
        for (int u = 0; u < 8; ++u) ones[u] = (__bf16)1.0f;

        f32x4 acc[2][4] = {};
        f32x4 accs[2]   = {};                        // row sums via P@ones
        float4 pa0[2], pa1[2];                       // prefetch registers
        #pragma unroll
        for (int it = 0; it < 2; ++it) {             // prefetch ks=0
            pa0[it] = *(const float4*)(arow[it] + quad * 8);
            pa1[it] = *(const float4*)(arow[it] + quad * 8 + 4);
        }
        for (int ks = 0; ks < 16; ++ks) {            // K = 512 neighbors
            int j0 = ks * 32 + quad * 8;
            f32x4 s0 = *(const f32x4*)&sm.sdst[j0];
            f32x4 s1 = *(const f32x4*)&sm.sdst[j0 + 4];
            float sd[8] = {s0[0],s0[1],s0[2],s0[3],s1[0],s1[1],s1[2],s1[3]};
            float am[2][8];
            #pragma unroll
            for (int it = 0; it < 2; ++it) {         // consume prefetch
                am[it][0]=pa0[it].x; am[it][1]=pa0[it].y;
                am[it][2]=pa0[it].z; am[it][3]=pa0[it].w;
                am[it][4]=pa1[it].x; am[it][5]=pa1[it].y;
                am[it][6]=pa1[it].z; am[it][7]=pa1[it].w;
            }
            if (ks < 15) {                           // issue ks+1 loads now;
                #pragma unroll                       // they fly over P-gen+MFMA
                for (int it = 0; it < 2; ++it) {
                    pa0[it] = *(const float4*)(arow[it] + j0 + 32);
                    pa1[it] = *(const float4*)(arow[it] + j0 + 36);
                }
            }
            bf16x8 P[2];
            #pragma unroll
            for (int it = 0; it < 2; ++it)
                #pragma unroll
                for (int u = 0; u < 8; ++u) {
                    float e = si[it] + sd[u];        // pre-scaled by log2e
                    float l = fmaxf(e, ALPHA * e);   // lrelu (pos-scale-invariant)
                    float p = am[it][u] * EXP2(l);   // mask by multiply
                    P[it][u] = (__bf16)p;
                }
            bf16x8 bv[4];
            #pragma unroll
            for (int nt = 0; nt < 4; ++nt)
                bv[nt] = *(const bf16x8*)(&sm.hT[nt * 16 + col][j0]);
            #pragma unroll
            for (int it = 0; it < 2; ++it) {
                #pragma unroll
                for (int nt = 0; nt < 4; ++nt)
                    acc[it][nt] = __builtin_amdgcn_mfma_f32_16x16x32_bf16(P[it], bv[nt], acc[it][nt], 0, 0, 0);
                accs[it] = __builtin_amdgcn_mfma_f32_16x16x32_bf16(P[it], ones, accs[it], 0, 0, 0);
            }
        }
        // epilogue: accs rows (quad*4+r) align with acc rows; no barrier
        #pragma unroll
        for (int it = 0; it < 2; ++it)
            #pragma unroll
            for (int r = 0; r < 4; ++r) {
                float s = accs[it][r];
                float inv = (s > 0.f) ? 1.0f / s : 0.f;
                int i = wave * 32 + it * 16 + quad * 4 + r;
                float* orow = out + ((long)b * 512 + i) * 512 + h * 64;
                #pragma unroll
                for (int nt = 0; nt < 4; ++nt)
                    orow[nt * 16 + col] = acc[it][nt][r] * inv;
            }
    }
}

// ---------------- launch ---------------------------------------------------
extern "C" void kernel_launch(void* const* d_in, const int* in_sizes, int n_in,
                              void* d_out, int out_size, void* d_ws, size_t ws_size,
                              hipStream_t stream) {
    const float* x   = (const float*)d_in[0];   // (32,512,256)
    const float* adj = (const float*)d_in[1];   // (32,512,512), {0,1}
    const float* W   = (const float*)d_in[2];   // (256,512)
    const float* a   = (const float*)d_in[3];   // (8,128)
    float* out = (float*)d_out;                 // (32,512,512)
    (void)d_ws; (void)ws_size;

    k_gat<<<dim3(32, 8), 1024, 0, stream>>>(x, adj, W, a, out);
}